// Round 4
// baseline (1179.562 us; speedup 1.0000x reference)
//
#include <hip/hip_runtime.h>

// ---------------------------------------------------------------------------
// ShiftedWindowAttention (Swin block, no mask): B=32, H=W=56, C=384, ws=7,
// shift=3, heads=12, hd=32.
//   prep:      weights -> bf16 [n][k]; bias -> C-frag order (+mask);
//              x -> bf16 (XB, aliases AO region); m->window LUT
//   qkv_gemm:  XB @ Wq^T -> Q,K,V bf16 [win][head][49][32]
//   attn:      4 waves/block, 1 wave per (win,head)
//   proj_gemm: AO @ Wp^T + proj_b -> out fp32
// R4: global_load_lds width=16 staging, linear LDS tiles.
// R5: 2-phase dbuf (null — __syncthreads drains vmcnt(0), no lead) + LUT
//     epilogue (VALU 44->23, no time change -> VALU off critical path).
// R7 (this round): both GEMMs -> 256x128 tile, 8 waves (512 thr), depth-2
//     counted-vmcnt pipeline: raw s_barrier + s_waitcnt vmcnt(3) so tile
//     t+1's loads stay in flight across barriers (T3/T4, m218 lever).
//     vmcnt ledger: 3 issues/wave/tile (A:2,B:1); prologue 6 outstanding;
//     iter t waits 3 (t landed, t+1 in flight); last iter waits 0;
//     stage(t+2) only after post-compute barrier (anti-overwrite).
// ---------------------------------------------------------------------------

typedef __attribute__((ext_vector_type(8))) short short8;
typedef __attribute__((ext_vector_type(4))) float floatx4;

#define CDIM  384
#define QKVN  1152
#define MROWS 100352      // 32*3136
#define LROW  3136        // 56*56

static constexpr size_t QKV_ELEMS = 38535168ull;   // 2048*12*49*32
static constexpr size_t OFF_Q    = 0;
static constexpr size_t OFF_K    = OFF_Q  + QKV_ELEMS * 2 + 4096;
static constexpr size_t OFF_V    = OFF_K  + QKV_ELEMS * 2 + 4096;
static constexpr size_t OFF_AO   = OFF_V  + QKV_ELEMS * 2 + 4096;  // also XB (x as bf16) before attn runs
static constexpr size_t OFF_WQ   = OFF_AO + (size_t)MROWS * CDIM * 2 + 4096;
static constexpr size_t OFF_WP   = OFF_WQ + (size_t)QKVN * CDIM * 2 + 256;
static constexpr size_t OFF_BIAS = OFF_WP + (size_t)CDIM * CDIM * 2 + 256;
static constexpr size_t OFF_LUT  = OFF_BIAS + (size_t)12 * 64 * 64 * 4 + 256;

__device__ __forceinline__ unsigned short f2bf(float f) {
  unsigned int u = __float_as_uint(f);
  unsigned int lsb = (u >> 16) & 1u;
  u += 0x7fffu + lsb;
  return (unsigned short)(u >> 16);
}

// direct global -> LDS async copy, 16B per lane. LDS dest must be
// wave-uniform base (+ lane*16 implicit); global src is per-lane.
__device__ __forceinline__ void gl2lds16(const void* g, void* l) {
  __builtin_amdgcn_global_load_lds(
      (const __attribute__((address_space(1))) unsigned int*)g,
      (__attribute__((address_space(3))) unsigned int*)l, 16, 0, 0);
}

// raw barrier / counted waitcnt (rule #18: sched_barrier(0) fences around)
#define RAW_BARRIER()                           \
  do {                                          \
    __builtin_amdgcn_sched_barrier(0);          \
    asm volatile("s_barrier" ::: "memory");     \
    __builtin_amdgcn_sched_barrier(0);          \
  } while (0)
#define WAIT_VM(N)                                        \
  do {                                                    \
    asm volatile("s_waitcnt vmcnt(" #N ")" ::: "memory"); \
    __builtin_amdgcn_sched_barrier(0);                    \
  } while (0)

// ---------------------------------------------------------------------------
// prep: weight transpose/convert + bias in C-frag order + x -> bf16 + LUT
// ---------------------------------------------------------------------------
__global__ __launch_bounds__(256) void prep_kernel(
    const float* __restrict__ x, const float* __restrict__ qkv_w,
    const float* __restrict__ proj_w, const float* __restrict__ rbt,
    char* __restrict__ ws) {
  unsigned short* Wq = (unsigned short*)(ws + OFF_WQ);
  unsigned short* Wp = (unsigned short*)(ws + OFF_WP);
  unsigned short* XB = (unsigned short*)(ws + OFF_AO);
  float* biasp = (float*)(ws + OFF_BIAS);
  int* lut = (int*)(ws + OFF_LUT);
  const int tid = blockIdx.x * blockDim.x + threadIdx.x;
  const int stride = gridDim.x * blockDim.x;
  for (int idx = tid; idx < QKVN * CDIM; idx += stride) {
    int n = idx / CDIM, k = idx - n * CDIM;
    Wq[idx] = f2bf(qkv_w[(size_t)k * QKVN + n]);
  }
  for (int idx = tid; idx < CDIM * CDIM; idx += stride) {
    int n = idx / CDIM, k = idx - n * CDIM;
    Wp[idx] = f2bf(proj_w[(size_t)k * CDIM + n]);
  }
  for (int idx = tid; idx < 12 * 64 * 64; idx += stride) {
    int h = idx / 4096;
    int rem = idx - h * 4096;
    int lane = rem / 64;
    int e = rem - lane * 64;        // (fm*4+fn)*4 + r
    int fm = e >> 4, fn = (e >> 2) & 3, r = e & 3;
    int row = fm * 16 + (lane >> 4) * 4 + r;
    int col = fn * 16 + (lane & 15);
    float v = -1e30f;
    if (row < 49 && col < 49) {
      int i = row / 7, j = row - i * 7;
      int k2 = col / 7, l2 = col - k2 * 7;
      int rpi = (i - k2 + 6) * 13 + (j - l2 + 6);
      v = rbt[rpi * 12 + h];
    }
    biasp[idx] = v;
  }
  // m -> scatter-base LUT: lut[m] = win*18816 + nidx*32
  for (int idx = tid; idx < MROWS; idx += stride) {
    int b_ = idx / LROW, l = idx - b_ * LROW;
    int y = l / 56, xx = l - y * 56;
    int yr = y + 53; if (yr >= 56) yr -= 56;   // roll -3
    int xr = xx + 53; if (xr >= 56) xr -= 56;
    int win = b_ * 64 + (yr / 7) * 8 + (xr / 7);
    int nidx = (yr % 7) * 7 + (xr % 7);
    lut[idx] = win * 18816 + nidx * 32;        // = ((win*12)*49 + nidx)*32
  }
  // x fp32 -> bf16, 8 elems/iter
  const size_t n8 = (size_t)MROWS * CDIM / 8;   // 4,816,896
  for (size_t idx = tid; idx < n8; idx += stride) {
    const float4* s = (const float4*)(x + idx * 8);
    float4 f0 = s[0], f1 = s[1];
    uint4 o;
    o.x = (unsigned)f2bf(f0.x) | ((unsigned)f2bf(f0.y) << 16);
    o.y = (unsigned)f2bf(f0.z) | ((unsigned)f2bf(f0.w) << 16);
    o.z = (unsigned)f2bf(f1.x) | ((unsigned)f2bf(f1.y) << 16);
    o.w = (unsigned)f2bf(f1.z) | ((unsigned)f2bf(f1.w) << 16);
    ((uint4*)XB)[idx] = o;
  }
}

// ---------------------------------------------------------------------------
// QKV GEMM: 100352x1152 = XB(bf16) @ Wq^T.  BM=256 BN=128 BK=32, 512 thr =
// 8 waves 4x2, per-wave 64x64 = 4x4 frags of 16x16x32 bf16.
// Depth-2 counted-vmcnt pipeline (see header).  Staging per wave per tile:
// A rows [wv*32, wv*32+32) = 2 issues, B rows [wv*16, wv*16+16) = 1 issue.
// Grid 3528 = 8 xcd * 49 * 9: xcd=L%8, slot=L/8, m=(slot/9*8+xcd)*256,
// n=(slot%9)*128 -> all 9 N-blocks of an M-group on one XCD.
// Epilogue: +bias, Q*=1/sqrt(32), scatter via lut to [win][head][n][d] bf16.
// ---------------------------------------------------------------------------
__global__ __launch_bounds__(512, 6) void qkv_gemm(
    const float* __restrict__ qkv_b, char* __restrict__ ws) {
  __shared__ unsigned short As[2][256][32];
  __shared__ unsigned short Bs[2][128][32];
  const unsigned short* XB = (const unsigned short*)(ws + OFF_AO);
  const unsigned short* Wq = (const unsigned short*)(ws + OFF_WQ);
  unsigned short* Qb = (unsigned short*)(ws + OFF_Q);
  unsigned short* Kb = (unsigned short*)(ws + OFF_K);
  unsigned short* Vb = (unsigned short*)(ws + OFF_V);
  const int* lut = (const int*)(ws + OFF_LUT);
  const int L = blockIdx.x;
  const int xcd = L & 7, slot = L >> 3;
  const int g9 = slot / 9;
  const int m0 = (g9 * 8 + xcd) * 256;
  const int n0 = (slot - g9 * 9) * 128;
  const int t = threadIdx.x;
  const int lane = t & 63, li = lane & 15, qd = lane >> 4;
  const int wv = t >> 6;            // 0..7
  const int wm = wv >> 1, wn = wv & 1;
  // staging coords: lane -> (row within 16-row chunk, 16B chunk in row)
  const int ld_r = lane >> 2;          // 0..15
  const int ld_c = (lane & 3) * 8;     // shorts
  const unsigned short* agp = XB + (size_t)(m0 + wv * 32 + ld_r) * CDIM + ld_c;
  const unsigned short* bgp = Wq + (size_t)(n0 + wv * 16 + ld_r) * CDIM + ld_c;

#define QSTAGE(buf, k0)                                          \
  do {                                                           \
    gl2lds16(agp + (k0),             &As[buf][wv * 32][0]);      \
    gl2lds16(agp + (k0) + 16 * CDIM, &As[buf][wv * 32 + 16][0]); \
    gl2lds16(bgp + (k0),             &Bs[buf][wv * 16][0]);      \
  } while (0)

  floatx4 acc[4][4] = {};
  QSTAGE(0, 0);        // tile 0 -> buf 0   (3 outstanding)
  QSTAGE(1, 32);       // tile 1 -> buf 1   (6 outstanding)
  for (int kt = 0; kt < 12; ++kt) {
    const int cur = kt & 1;
    if (kt < 11) { WAIT_VM(3); }   // tile kt landed; tile kt+1 in flight
    else         { WAIT_VM(0); }
    RAW_BARRIER();                 // all waves' tile-kt portions visible
    short8 a[4], b[4];
#pragma unroll
    for (int f = 0; f < 4; f++)
      a[f] = *(const short8*)&As[cur][wm * 64 + f * 16 + li][qd * 8];
#pragma unroll
    for (int f = 0; f < 4; f++)
      b[f] = *(const short8*)&Bs[cur][wn * 64 + f * 16 + li][qd * 8];
#pragma unroll
    for (int i = 0; i < 4; i++)
#pragma unroll
      for (int j = 0; j < 4; j++)
        acc[i][j] = __builtin_amdgcn_mfma_f32_16x16x32_bf16(a[i], b[j], acc[i][j], 0, 0, 0);
    RAW_BARRIER();                 // all waves done reading buf[cur]
    if (kt + 2 < 12) QSTAGE(cur, (kt + 2) * 32);   // overwrite buf[cur]
  }
#undef QSTAGE

  // epilogue: each 128-wide N-tile lies entirely in one of Q/K/V (384 = 3*128)
  const int which = n0 / CDIM;
  unsigned short* dst = which == 0 ? Qb : (which == 1 ? Kb : Vb);
  const float mul = (which == 0) ? 0.17677669529663689f : 1.0f;
#pragma unroll
  for (int i = 0; i < 4; i++) {
    int lbase[4];
#pragma unroll
    for (int r = 0; r < 4; r++)
      lbase[r] = lut[m0 + wm * 64 + i * 16 + qd * 4 + r];
#pragma unroll
    for (int j = 0; j < 4; j++) {
      int c = n0 + wn * 64 + j * 16 + li;
      int cc = c - which * CDIM;
      int head = cc >> 5, d = cc & 31;
      int hd_off = head * 1568 + d;          // head*49*32 + d
      float bval = qkv_b[c];
#pragma unroll
      for (int r = 0; r < 4; r++) {
        size_t off = (size_t)(lbase[r] + hd_off);
        dst[off] = f2bf((acc[i][j][r] + bval) * mul);
      }
    }
  }
}

// ---------------------------------------------------------------------------
// Attention: 256 thr = 4 waves, wave wv handles head blockIdx.y*4+wv of
// window blockIdx.x.  Per-wave LDS region SMEM[wv]: first holds V (stride-34
// layout, rows 49..63 zeroed), V frags -> regs, then overwritten by P
// (stride-72).  No __syncthreads (no cross-wave sharing).
// ---------------------------------------------------------------------------
__global__ __launch_bounds__(256) void attn_kernel(char* __restrict__ ws) {
  __shared__ unsigned short SMEM[4][64 * 72];
  const int win = blockIdx.x;
  const int t = threadIdx.x, wv = t >> 6, lane = t & 63;
  const int h = blockIdx.y * 4 + wv;
  const int li = lane & 15, qd = lane >> 4;
  unsigned short* Sm = &SMEM[wv][0];
  const size_t whoff = (size_t)(win * 12 + h) * 49 * 32;
  const unsigned short* Qb = (const unsigned short*)(ws + OFF_Q) + whoff;
  const unsigned short* Kb = (const unsigned short*)(ws + OFF_K) + whoff;
  const unsigned short* Vb = (const unsigned short*)(ws + OFF_V) + whoff;
  const float* biasp = (const float*)(ws + OFF_BIAS) + ((size_t)h * 64 + lane) * 64;

  // stage V: 49 rows x 32 cols bf16 = 392 uint2, LDS stride 34
  {
    const uint2* vsrc = (const uint2*)Vb;
    for (int idx = lane; idx < 392; idx += 64) {
      uint2 d = vsrc[idx];
      unsigned short* p = Sm + (idx >> 3) * 34 + (idx & 7) * 4;
      *(unsigned int*)p = d.x;
      *(unsigned int*)(p + 2) = d.y;
    }
    for (int idx = lane; idx < 120; idx += 64) {   // zero pad rows 49..63
      unsigned short* p = Sm + (49 + (idx >> 3)) * 34 + (idx & 7) * 4;
      *(unsigned int*)p = 0;
      *(unsigned int*)(p + 2) = 0;
    }
  }

  short8 qa[4], kb4[4];
#pragma unroll
  for (int f = 0; f < 4; f++) {
    qa[f] = *(const short8*)(Qb + (f * 16 + li) * 32 + qd * 8);
    kb4[f] = *(const short8*)(Kb + (f * 16 + li) * 32 + qd * 8);
  }
  floatx4 s[4][4] = {};
#pragma unroll
  for (int i = 0; i < 4; i++)
#pragma unroll
    for (int j = 0; j < 4; j++)
      s[i][j] = __builtin_amdgcn_mfma_f32_16x16x32_bf16(qa[i], kb4[j], s[i][j], 0, 0, 0);

  // V B-frags from LDS (before P overwrites the region)
  short8 vb[2][2];
#pragma unroll
  for (int ss = 0; ss < 2; ss++)
#pragma unroll
    for (int nf = 0; nf < 2; nf++) {
      short8 tmp;
#pragma unroll
      for (int j = 0; j < 8; j++)
        tmp[j] = (short)Sm[(ss * 32 + qd * 8 + j) * 34 + nf * 16 + li];
      vb[ss][nf] = tmp;
    }

  float rsum[4][4];
#pragma unroll
  for (int fm = 0; fm < 4; fm++) {
#pragma unroll
    for (int fn = 0; fn < 4; fn++) {
      floatx4 bv = *(const floatx4*)(biasp + (fm * 4 + fn) * 4);
#pragma unroll
      for (int r = 0; r < 4; r++)
        s[fm][fn][r] = __expf(s[fm][fn][r] + bv[r]);
    }
#pragma unroll
    for (int r = 0; r < 4; r++) {
      float v = s[fm][0][r] + s[fm][1][r] + s[fm][2][r] + s[fm][3][r];
      v += __shfl_xor(v, 1);
      v += __shfl_xor(v, 2);
      v += __shfl_xor(v, 4);
      v += __shfl_xor(v, 8);
      rsum[fm][r] = v;
    }
#pragma unroll
    for (int fn = 0; fn < 4; fn++)
#pragma unroll
      for (int r = 0; r < 4; r++)
        Sm[(fm * 16 + qd * 4 + r) * 72 + fn * 16 + li] = f2bf(s[fm][fn][r]);
  }

  floatx4 o[4][2] = {};
#pragma unroll
  for (int fm = 0; fm < 4; fm++)
#pragma unroll
    for (int ss = 0; ss < 2; ss++) {
      short8 pa = *(const short8*)&Sm[(fm * 16 + li) * 72 + ss * 32 + qd * 8];
#pragma unroll
      for (int nf = 0; nf < 2; nf++)
        o[fm][nf] = __builtin_amdgcn_mfma_f32_16x16x32_bf16(pa, vb[ss][nf], o[fm][nf], 0, 0, 0);
    }

  unsigned short* AO = (unsigned short*)(ws + OFF_AO);
  const int b_ = win >> 6, wrem = win & 63, wy = wrem >> 3, wx = wrem & 7;
#pragma unroll
  for (int fm = 0; fm < 4; fm++)
#pragma unroll
    for (int r = 0; r < 4; r++) {
      int n = fm * 16 + qd * 4 + r;
      if (n >= 49) continue;
      float inv = 1.0f / rsum[fm][r];
      int i_ = n / 7, j_ = n - i_ * 7;
      int y = wy * 7 + i_ + 3;  if (y >= 56) y -= 56;   // un-roll +3
      int xx = wx * 7 + j_ + 3; if (xx >= 56) xx -= 56;
      size_t base = ((size_t)b_ * LROW + y * 56 + xx) * CDIM + h * 32;
#pragma unroll
      for (int nf = 0; nf < 2; nf++)
        AO[base + nf * 16 + li] = f2bf(o[fm][nf][r] * inv);
    }
}

// ---------------------------------------------------------------------------
// Proj GEMM: out(100352x384 fp32) = AO(bf16) @ Wp^T + proj_b.  Same depth-2
// counted-vmcnt 256x128 structure; grid 1176 = 8 xcd * 49 * 3.
// ---------------------------------------------------------------------------
__global__ __launch_bounds__(512, 6) void proj_gemm(
    const float* __restrict__ proj_b, char* __restrict__ ws,
    float* __restrict__ out) {
  __shared__ unsigned short As[2][256][32];
  __shared__ unsigned short Bs[2][128][32];
  const unsigned short* AO = (const unsigned short*)(ws + OFF_AO);
  const unsigned short* Wp = (const unsigned short*)(ws + OFF_WP);
  const int L = blockIdx.x;
  const int xcd = L & 7, slot = L >> 3;
  const int g3 = slot / 3;
  const int m0 = (g3 * 8 + xcd) * 256;
  const int n0 = (slot - g3 * 3) * 128;
  const int t = threadIdx.x;
  const int lane = t & 63, li = lane & 15, qd = lane >> 4;
  const int wv = t >> 6;
  const int wm = wv >> 1, wn = wv & 1;
  const int ld_r = lane >> 2;
  const int ld_c = (lane & 3) * 8;
  const unsigned short* agp = AO + (size_t)(m0 + wv * 32 + ld_r) * CDIM + ld_c;
  const unsigned short* bgp = Wp + (size_t)(n0 + wv * 16 + ld_r) * CDIM + ld_c;

#define PSTAGE(buf, k0)                                          \
  do {                                                           \
    gl2lds16(agp + (k0),             &As[buf][wv * 32][0]);      \
    gl2lds16(agp + (k0) + 16 * CDIM, &As[buf][wv * 32 + 16][0]); \
    gl2lds16(bgp + (k0),             &Bs[buf][wv * 16][0]);      \
  } while (0)

  floatx4 acc[4][4] = {};
  PSTAGE(0, 0);
  PSTAGE(1, 32);
  for (int kt = 0; kt < 12; ++kt) {
    const int cur = kt & 1;
    if (kt < 11) { WAIT_VM(3); }
    else         { WAIT_VM(0); }
    RAW_BARRIER();
    short8 a[4], b[4];
#pragma unroll
    for (int f = 0; f < 4; f++)
      a[f] = *(const short8*)&As[cur][wm * 64 + f * 16 + li][qd * 8];
#pragma unroll
    for (int f = 0; f < 4; f++)
      b[f] = *(const short8*)&Bs[cur][wn * 64 + f * 16 + li][qd * 8];
#pragma unroll
    for (int i = 0; i < 4; i++)
#pragma unroll
      for (int j = 0; j < 4; j++)
        acc[i][j] = __builtin_amdgcn_mfma_f32_16x16x32_bf16(a[i], b[j], acc[i][j], 0, 0, 0);
    RAW_BARRIER();
    if (kt + 2 < 12) PSTAGE(cur, (kt + 2) * 32);
  }
#undef PSTAGE

#pragma unroll
  for (int i = 0; i < 4; i++)
#pragma unroll
    for (int j = 0; j < 4; j++) {
      int c = n0 + wn * 64 + j * 16 + li;
      float bv = proj_b[c];
#pragma unroll
      for (int r = 0; r < 4; r++) {
        int m = m0 + wm * 64 + i * 16 + qd * 4 + r;
        out[(size_t)m * CDIM + c] = acc[i][j][r] + bv;
      }
    }
}

extern "C" void kernel_launch(void* const* d_in, const int* in_sizes, int n_in,
                              void* d_out, int out_size, void* d_ws, size_t ws_size,
                              hipStream_t stream) {
  const float* x      = (const float*)d_in[0];
  const float* qkv_w  = (const float*)d_in[1];
  const float* qkv_b  = (const float*)d_in[2];
  const float* proj_w = (const float*)d_in[3];
  const float* proj_b = (const float*)d_in[4];
  const float* rbt    = (const float*)d_in[5];
  char* ws = (char*)d_ws;
  float* out = (float*)d_out;

  prep_kernel<<<2048, 256, 0, stream>>>(x, qkv_w, proj_w, rbt, ws);
  qkv_gemm<<<3528, 512, 0, stream>>>(qkv_b, ws);
  attn_kernel<<<dim3(2048, 3), 256, 0, stream>>>(ws);
  proj_gemm<<<1176, 512, 0, stream>>>(proj_b, ws, out);
}

// Round 5
// 613.364 us; speedup vs baseline: 1.9231x; 1.9231x over previous
//
#include <hip/hip_runtime.h>

// ---------------------------------------------------------------------------
// ShiftedWindowAttention (Swin block, no mask): B=32, H=W=56, C=384, ws=7,
// shift=3, heads=12, hd=32.
//   prep:      weights -> bf16 [n][k]; bias -> C-frag order (+mask);
//              x -> bf16 (XB, aliases AO region); m->window LUT
//   qkv_gemm:  XB @ Wq^T -> Q,K,V bf16 [win][head][49][32]
//   attn:      4 waves/block, 1 wave per (win,head)
//   proj_gemm: AO @ Wp^T + proj_b -> out fp32
// R4: global_load_lds width=16 staging, linear LDS tiles.
// R5: 2-phase dbuf (null: __syncthreads drains vmcnt(0)) + LUT epilogue.
// R7: 256x128/512thr + launch_bounds(512,6) -> VGPR cap 85 < acc(64)+ops ->
//     SPILL (VGPR_Count 40), scratch thrash, 3.4x slower.  REVERTED.
// R8 (this round): R6 geometry (128x128, 256 thr, launch_bounds(256)) with
//     counted-vmcnt depth-2 pipeline: raw s_barrier + s_waitcnt vmcnt(4).
//     Ledger: 4 gload_lds/wave/tile; prologue 8 outstanding; iter kt waits 4
//     (tile kt landed, kt+1 in flight ACROSS barriers); stage kt+2 after the
//     post-compute barrier; last iter waits 0.
//     attn: Q/K loads issued before V stage; V stored transposed
//     (Vt[d][row], stride 72, cols 49..63 zeroed) -> V frags via 4
//     ds_read_b128 instead of 32 ds_read_u16.
// ---------------------------------------------------------------------------

typedef __attribute__((ext_vector_type(8))) short short8;
typedef __attribute__((ext_vector_type(4))) float floatx4;

#define CDIM  384
#define QKVN  1152
#define MROWS 100352      // 32*3136
#define LROW  3136        // 56*56

static constexpr size_t QKV_ELEMS = 38535168ull;   // 2048*12*49*32
static constexpr size_t OFF_Q    = 0;
static constexpr size_t OFF_K    = OFF_Q  + QKV_ELEMS * 2 + 4096;
static constexpr size_t OFF_V    = OFF_K  + QKV_ELEMS * 2 + 4096;
static constexpr size_t OFF_AO   = OFF_V  + QKV_ELEMS * 2 + 4096;  // also XB (x as bf16) before attn runs
static constexpr size_t OFF_WQ   = OFF_AO + (size_t)MROWS * CDIM * 2 + 4096;
static constexpr size_t OFF_WP   = OFF_WQ + (size_t)QKVN * CDIM * 2 + 256;
static constexpr size_t OFF_BIAS = OFF_WP + (size_t)CDIM * CDIM * 2 + 256;
static constexpr size_t OFF_LUT  = OFF_BIAS + (size_t)12 * 64 * 64 * 4 + 256;

__device__ __forceinline__ unsigned short f2bf(float f) {
  unsigned int u = __float_as_uint(f);
  unsigned int lsb = (u >> 16) & 1u;
  u += 0x7fffu + lsb;
  return (unsigned short)(u >> 16);
}

// direct global -> LDS async copy, 16B per lane. LDS dest must be
// wave-uniform base (+ lane*16 implicit); global src is per-lane.
__device__ __forceinline__ void gl2lds16(const void* g, void* l) {
  __builtin_amdgcn_global_load_lds(
      (const __attribute__((address_space(1))) unsigned int*)g,
      (__attribute__((address_space(3))) unsigned int*)l, 16, 0, 0);
}

// raw barrier / counted waitcnt (rule #18: sched_barrier(0) fences)
#define RAW_BARRIER()                           \
  do {                                          \
    __builtin_amdgcn_sched_barrier(0);          \
    asm volatile("s_barrier" ::: "memory");     \
    __builtin_amdgcn_sched_barrier(0);          \
  } while (0)
#define WAIT_VM(N)                                        \
  do {                                                    \
    asm volatile("s_waitcnt vmcnt(" #N ")" ::: "memory"); \
    __builtin_amdgcn_sched_barrier(0);                    \
  } while (0)

// ---------------------------------------------------------------------------
// prep: weight transpose/convert + bias in C-frag order + x -> bf16 + LUT
// ---------------------------------------------------------------------------
__global__ __launch_bounds__(256) void prep_kernel(
    const float* __restrict__ x, const float* __restrict__ qkv_w,
    const float* __restrict__ proj_w, const float* __restrict__ rbt,
    char* __restrict__ ws) {
  unsigned short* Wq = (unsigned short*)(ws + OFF_WQ);
  unsigned short* Wp = (unsigned short*)(ws + OFF_WP);
  unsigned short* XB = (unsigned short*)(ws + OFF_AO);
  float* biasp = (float*)(ws + OFF_BIAS);
  int* lut = (int*)(ws + OFF_LUT);
  const int tid = blockIdx.x * blockDim.x + threadIdx.x;
  const int stride = gridDim.x * blockDim.x;
  for (int idx = tid; idx < QKVN * CDIM; idx += stride) {
    int n = idx / CDIM, k = idx - n * CDIM;
    Wq[idx] = f2bf(qkv_w[(size_t)k * QKVN + n]);
  }
  for (int idx = tid; idx < CDIM * CDIM; idx += stride) {
    int n = idx / CDIM, k = idx - n * CDIM;
    Wp[idx] = f2bf(proj_w[(size_t)k * CDIM + n]);
  }
  for (int idx = tid; idx < 12 * 64 * 64; idx += stride) {
    int h = idx / 4096;
    int rem = idx - h * 4096;
    int lane = rem / 64;
    int e = rem - lane * 64;        // (fm*4+fn)*4 + r
    int fm = e >> 4, fn = (e >> 2) & 3, r = e & 3;
    int row = fm * 16 + (lane >> 4) * 4 + r;
    int col = fn * 16 + (lane & 15);
    float v = -1e30f;
    if (row < 49 && col < 49) {
      int i = row / 7, j = row - i * 7;
      int k2 = col / 7, l2 = col - k2 * 7;
      int rpi = (i - k2 + 6) * 13 + (j - l2 + 6);
      v = rbt[rpi * 12 + h];
    }
    biasp[idx] = v;
  }
  // m -> scatter-base LUT: lut[m] = win*18816 + nidx*32
  for (int idx = tid; idx < MROWS; idx += stride) {
    int b_ = idx / LROW, l = idx - b_ * LROW;
    int y = l / 56, xx = l - y * 56;
    int yr = y + 53; if (yr >= 56) yr -= 56;   // roll -3
    int xr = xx + 53; if (xr >= 56) xr -= 56;
    int win = b_ * 64 + (yr / 7) * 8 + (xr / 7);
    int nidx = (yr % 7) * 7 + (xr % 7);
    lut[idx] = win * 18816 + nidx * 32;        // = ((win*12)*49 + nidx)*32
  }
  // x fp32 -> bf16, 8 elems/iter
  const size_t n8 = (size_t)MROWS * CDIM / 8;   // 4,816,896
  for (size_t idx = tid; idx < n8; idx += stride) {
    const float4* s = (const float4*)(x + idx * 8);
    float4 f0 = s[0], f1 = s[1];
    uint4 o;
    o.x = (unsigned)f2bf(f0.x) | ((unsigned)f2bf(f0.y) << 16);
    o.y = (unsigned)f2bf(f0.z) | ((unsigned)f2bf(f0.w) << 16);
    o.z = (unsigned)f2bf(f1.x) | ((unsigned)f2bf(f1.y) << 16);
    o.w = (unsigned)f2bf(f1.z) | ((unsigned)f2bf(f1.w) << 16);
    ((uint4*)XB)[idx] = o;
  }
}

// ---------------------------------------------------------------------------
// QKV GEMM: 100352x1152 = XB(bf16) @ Wq^T.  BM=128 BN=128 BK=32, 256 thr =
// 4 waves 2x2, per-wave 64x64 = 4x4 frags of 16x16x32 bf16.
// Counted-vmcnt depth-2 pipeline (see header).  4 gload_lds/wave/tile.
// Linear grid 7056, swizzle: xcd=L%8, slot=L/8, m=(slot/9)*8+xcd, n=slot%9
// -> all 9 N-blocks of an M-row-block on one XCD (A fetched once from HBM).
// Epilogue: +bias, Q*=1/sqrt(32), scatter via lut to [win][head][n][d] bf16.
// ---------------------------------------------------------------------------
__global__ __launch_bounds__(256) void qkv_gemm(
    const float* __restrict__ qkv_b, char* __restrict__ ws) {
  __shared__ unsigned short As[2][128][32];
  __shared__ unsigned short Bs[2][128][32];
  const unsigned short* XB = (const unsigned short*)(ws + OFF_AO);
  const unsigned short* Wq = (const unsigned short*)(ws + OFF_WQ);
  unsigned short* Qb = (unsigned short*)(ws + OFF_Q);
  unsigned short* Kb = (unsigned short*)(ws + OFF_K);
  unsigned short* Vb = (unsigned short*)(ws + OFF_V);
  const int* lut = (const int*)(ws + OFF_LUT);
  const int L = blockIdx.x;
  const int xcd = L & 7, slot = L >> 3;
  const int g9 = slot / 9;
  const int m0 = (g9 * 8 + xcd) * 128;
  const int n0 = (slot - g9 * 9) * 128;
  const int t = threadIdx.x;
  const int lane = t & 63, li = lane & 15, qd = lane >> 4;
  const int wv = t >> 6, wm = wv >> 1, wn = wv & 1;
  // staging coords: lane -> (row within 16-row chunk, 16B chunk in row)
  const int ld_r = lane >> 2;          // 0..15
  const int ld_c = (lane & 3) * 8;     // shorts
  const unsigned short* agp = XB + (size_t)(m0 + wv * 32 + ld_r) * CDIM + ld_c;
  const unsigned short* bgp = Wq + (size_t)(n0 + wv * 32 + ld_r) * CDIM + ld_c;

#define QSTAGE(buf, k0)                                          \
  do {                                                           \
    gl2lds16(agp + (k0),             &As[buf][wv * 32][0]);      \
    gl2lds16(agp + (k0) + 16 * CDIM, &As[buf][wv * 32 + 16][0]); \
    gl2lds16(bgp + (k0),             &Bs[buf][wv * 32][0]);      \
    gl2lds16(bgp + (k0) + 16 * CDIM, &Bs[buf][wv * 32 + 16][0]); \
  } while (0)

  floatx4 acc[4][4] = {};
  QSTAGE(0, 0);        // tile 0 -> buf 0  (4 outstanding)
  QSTAGE(1, 32);       // tile 1 -> buf 1  (8 outstanding)
  for (int kt = 0; kt < 12; ++kt) {
    const int cur = kt & 1;
    if (kt < 11) { WAIT_VM(4); }   // tile kt landed; tile kt+1 stays in flight
    else         { WAIT_VM(0); }
    RAW_BARRIER();                 // all waves' tile-kt portions visible
    short8 a[4], b[4];
#pragma unroll
    for (int f = 0; f < 4; f++)
      a[f] = *(const short8*)&As[cur][wm * 64 + f * 16 + li][qd * 8];
#pragma unroll
    for (int f = 0; f < 4; f++)
      b[f] = *(const short8*)&Bs[cur][wn * 64 + f * 16 + li][qd * 8];
#pragma unroll
    for (int i = 0; i < 4; i++)
#pragma unroll
      for (int j = 0; j < 4; j++)
        acc[i][j] = __builtin_amdgcn_mfma_f32_16x16x32_bf16(a[i], b[j], acc[i][j], 0, 0, 0);
    RAW_BARRIER();                 // all waves done reading buf[cur]
    if (kt + 2 < 12) QSTAGE(cur, (kt + 2) * 32);   // overwrite buf[cur]
  }
#undef QSTAGE

  // epilogue: each 128-wide N-tile lies entirely in one of Q/K/V (384 = 3*128)
  const int which = n0 / CDIM;
  unsigned short* dst = which == 0 ? Qb : (which == 1 ? Kb : Vb);
  const float mul = (which == 0) ? 0.17677669529663689f : 1.0f;
#pragma unroll
  for (int i = 0; i < 4; i++) {
    int lbase[4];
#pragma unroll
    for (int r = 0; r < 4; r++)
      lbase[r] = lut[m0 + wm * 64 + i * 16 + qd * 4 + r];
#pragma unroll
    for (int j = 0; j < 4; j++) {
      int c = n0 + wn * 64 + j * 16 + li;
      int cc = c - which * CDIM;
      int head = cc >> 5, d = cc & 31;
      int hd_off = head * 1568 + d;          // head*49*32 + d
      float bval = qkv_b[c];
#pragma unroll
      for (int r = 0; r < 4; r++) {
        size_t off = (size_t)(lbase[r] + hd_off);
        dst[off] = f2bf((acc[i][j][r] + bval) * mul);
      }
    }
  }
}

// ---------------------------------------------------------------------------
// Attention: 256 thr = 4 waves, wave wv handles head blockIdx.y*4+wv of
// window blockIdx.x.  Per-wave LDS region SMEM[wv]: first holds V transposed
// (Vt[d=0..31][row], stride 72, cols 49..63 zeroed), V frags -> regs via
// ds_read_b128, then region overwritten by P (stride-72).  Q/K register
// loads issued FIRST so HBM latency overlaps staging.  No __syncthreads.
// ---------------------------------------------------------------------------
__global__ __launch_bounds__(256) void attn_kernel(char* __restrict__ ws) {
  __shared__ unsigned short SMEM[4][64 * 72];
  const int win = blockIdx.x;
  const int t = threadIdx.x, wv = t >> 6, lane = t & 63;
  const int h = blockIdx.y * 4 + wv;
  const int li = lane & 15, qd = lane >> 4;
  unsigned short* Sm = &SMEM[wv][0];
  const size_t whoff = (size_t)(win * 12 + h) * 49 * 32;
  const unsigned short* Qb = (const unsigned short*)(ws + OFF_Q) + whoff;
  const unsigned short* Kb = (const unsigned short*)(ws + OFF_K) + whoff;
  const unsigned short* Vb = (const unsigned short*)(ws + OFF_V) + whoff;
  const float* biasp = (const float*)(ws + OFF_BIAS) + ((size_t)h * 64 + lane) * 64;

  // 1) issue Q/K fragment loads first (latency overlaps V staging below)
  short8 qa[4], kb4[4];
#pragma unroll
  for (int f = 0; f < 4; f++) {
    qa[f] = *(const short8*)(Qb + (f * 16 + li) * 32 + qd * 8);
    kb4[f] = *(const short8*)(Kb + (f * 16 + li) * 32 + qd * 8);
  }

  // 2) stage V transposed: Vt[d][row] at stride 72 (rows 0..31 of Sm).
  //    zero cols 48..63 first (stage overwrites col 48 with real data;
  //    same-wave DS ops are processed in order).
  for (int idx = lane; idx < 512; idx += 64) {     // 32 d * 16 cols
    Sm[(idx >> 4) * 72 + 48 + (idx & 15)] = 0;
  }
  {
    const uint2* vsrc = (const uint2*)Vb;
    for (int idx = lane; idx < 392; idx += 64) {   // 49 rows * 8 chunks
      uint2 dv = vsrc[idx];
      int row = idx >> 3, d0 = (idx & 7) * 4;
      Sm[(d0 + 0) * 72 + row] = (unsigned short)(dv.x & 0xffff);
      Sm[(d0 + 1) * 72 + row] = (unsigned short)(dv.x >> 16);
      Sm[(d0 + 2) * 72 + row] = (unsigned short)(dv.y & 0xffff);
      Sm[(d0 + 3) * 72 + row] = (unsigned short)(dv.y >> 16);
    }
  }

  // 3) QK^T
  floatx4 s[4][4] = {};
#pragma unroll
  for (int i = 0; i < 4; i++)
#pragma unroll
    for (int j = 0; j < 4; j++)
      s[i][j] = __builtin_amdgcn_mfma_f32_16x16x32_bf16(qa[i], kb4[j], s[i][j], 0, 0, 0);

  // 4) V B-frags from Vt (before P overwrites the region):
  //    vb[ss][nf][j] = V[ss*32+qd*8+j][nf*16+li] = Vt[nf*16+li][ss*32+qd*8+j]
  short8 vb[2][2];
#pragma unroll
  for (int ss = 0; ss < 2; ss++)
#pragma unroll
    for (int nf = 0; nf < 2; nf++)
      vb[ss][nf] = *(const short8*)&Sm[(nf * 16 + li) * 72 + ss * 32 + qd * 8];

  // 5) softmax numerator + row sums + P -> LDS (stride 72)
  float rsum[4][4];
#pragma unroll
  for (int fm = 0; fm < 4; fm++) {
#pragma unroll
    for (int fn = 0; fn < 4; fn++) {
      floatx4 bv = *(const floatx4*)(biasp + (fm * 4 + fn) * 4);
#pragma unroll
      for (int r = 0; r < 4; r++)
        s[fm][fn][r] = __expf(s[fm][fn][r] + bv[r]);
    }
#pragma unroll
    for (int r = 0; r < 4; r++) {
      float v = s[fm][0][r] + s[fm][1][r] + s[fm][2][r] + s[fm][3][r];
      v += __shfl_xor(v, 1);
      v += __shfl_xor(v, 2);
      v += __shfl_xor(v, 4);
      v += __shfl_xor(v, 8);
      rsum[fm][r] = v;
    }
#pragma unroll
    for (int fn = 0; fn < 4; fn++)
#pragma unroll
      for (int r = 0; r < 4; r++)
        Sm[(fm * 16 + qd * 4 + r) * 72 + fn * 16 + li] = f2bf(s[fm][fn][r]);
  }

  // 6) PV
  floatx4 o[4][2] = {};
#pragma unroll
  for (int fm = 0; fm < 4; fm++)
#pragma unroll
    for (int ss = 0; ss < 2; ss++) {
      short8 pa = *(const short8*)&Sm[(fm * 16 + li) * 72 + ss * 32 + qd * 8];
#pragma unroll
      for (int nf = 0; nf < 2; nf++)
        o[fm][nf] = __builtin_amdgcn_mfma_f32_16x16x32_bf16(pa, vb[ss][nf], o[fm][nf], 0, 0, 0);
    }

  // 7) normalize + scatter to AO (un-roll +3)
  unsigned short* AO = (unsigned short*)(ws + OFF_AO);
  const int b_ = win >> 6, wrem = win & 63, wy = wrem >> 3, wx = wrem & 7;
#pragma unroll
  for (int fm = 0; fm < 4; fm++)
#pragma unroll
    for (int r = 0; r < 4; r++) {
      int n = fm * 16 + qd * 4 + r;
      if (n >= 49) continue;
      float inv = 1.0f / rsum[fm][r];
      int i_ = n / 7, j_ = n - i_ * 7;
      int y = wy * 7 + i_ + 3;  if (y >= 56) y -= 56;
      int xx = wx * 7 + j_ + 3; if (xx >= 56) xx -= 56;
      size_t base = ((size_t)b_ * LROW + y * 56 + xx) * CDIM + h * 32;
#pragma unroll
      for (int nf = 0; nf < 2; nf++)
        AO[base + nf * 16 + li] = f2bf(o[fm][nf][r] * inv);
    }
}

// ---------------------------------------------------------------------------
// Proj GEMM: out(100352x384 fp32) = AO(bf16) @ Wp^T + proj_b.  Same
// counted-vmcnt depth-2 128x128 structure; grid 2352: m=(slot/3)*8+xcd,
// n=slot%3.
// ---------------------------------------------------------------------------
__global__ __launch_bounds__(256) void proj_gemm(
    const float* __restrict__ proj_b, char* __restrict__ ws,
    float* __restrict__ out) {
  __shared__ unsigned short As[2][128][32];
  __shared__ unsigned short Bs[2][128][32];
  const unsigned short* AO = (const unsigned short*)(ws + OFF_AO);
  const unsigned short* Wp = (const unsigned short*)(ws + OFF_WP);
  const int L = blockIdx.x;
  const int xcd = L & 7, slot = L >> 3;
  const int g3 = slot / 3;
  const int m0 = (g3 * 8 + xcd) * 128;
  const int n0 = (slot - g3 * 3) * 128;
  const int t = threadIdx.x;
  const int lane = t & 63, li = lane & 15, qd = lane >> 4;
  const int wv = t >> 6, wm = wv >> 1, wn = wv & 1;
  const int ld_r = lane >> 2;
  const int ld_c = (lane & 3) * 8;
  const unsigned short* agp = AO + (size_t)(m0 + wv * 32 + ld_r) * CDIM + ld_c;
  const unsigned short* bgp = Wp + (size_t)(n0 + wv * 32 + ld_r) * CDIM + ld_c;

#define PSTAGE(buf, k0)                                          \
  do {                                                           \
    gl2lds16(agp + (k0),             &As[buf][wv * 32][0]);      \
    gl2lds16(agp + (k0) + 16 * CDIM, &As[buf][wv * 32 + 16][0]); \
    gl2lds16(bgp + (k0),             &Bs[buf][wv * 32][0]);      \
    gl2lds16(bgp + (k0) + 16 * CDIM, &Bs[buf][wv * 32 + 16][0]); \
  } while (0)

  floatx4 acc[4][4] = {};
  PSTAGE(0, 0);
  PSTAGE(1, 32);
  for (int kt = 0; kt < 12; ++kt) {
    const int cur = kt & 1;
    if (kt < 11) { WAIT_VM(4); }
    else         { WAIT_VM(0); }
    RAW_BARRIER();
    short8 a[4], b[4];
#pragma unroll
    for (int f = 0; f < 4; f++)
      a[f] = *(const short8*)&As[cur][wm * 64 + f * 16 + li][qd * 8];
#pragma unroll
    for (int f = 0; f < 4; f++)
      b[f] = *(const short8*)&Bs[cur][wn * 64 + f * 16 + li][qd * 8];
#pragma unroll
    for (int i = 0; i < 4; i++)
#pragma unroll
      for (int j = 0; j < 4; j++)
        acc[i][j] = __builtin_amdgcn_mfma_f32_16x16x32_bf16(a[i], b[j], acc[i][j], 0, 0, 0);
    RAW_BARRIER();
    if (kt + 2 < 12) PSTAGE(cur, (kt + 2) * 32);
  }
#undef PSTAGE

#pragma unroll
  for (int i = 0; i < 4; i++)
#pragma unroll
    for (int j = 0; j < 4; j++) {
      int c = n0 + wn * 64 + j * 16 + li;
      float bv = proj_b[c];
#pragma unroll
      for (int r = 0; r < 4; r++) {
        int m = m0 + wm * 64 + i * 16 + qd * 4 + r;
        out[(size_t)m * CDIM + c] = acc[i][j][r] + bv;
      }
    }
}

extern "C" void kernel_launch(void* const* d_in, const int* in_sizes, int n_in,
                              void* d_out, int out_size, void* d_ws, size_t ws_size,
                              hipStream_t stream) {
  const float* x      = (const float*)d_in[0];
  const float* qkv_w  = (const float*)d_in[1];
  const float* qkv_b  = (const float*)d_in[2];
  const float* proj_w = (const float*)d_in[3];
  const float* proj_b = (const float*)d_in[4];
  const float* rbt    = (const float*)d_in[5];
  char* ws = (char*)d_ws;
  float* out = (float*)d_out;

  prep_kernel<<<2048, 256, 0, stream>>>(x, qkv_w, proj_w, rbt, ws);
  qkv_gemm<<<7056, 256, 0, stream>>>(qkv_b, ws);
  attn_kernel<<<dim3(2048, 3), 256, 0, stream>>>(ws);
  proj_gemm<<<2352, 256, 0, stream>>>(proj_b, ws, out);
}